// Round 4
// baseline (281.334 us; speedup 1.0000x reference)
//
#include <hip/hip_runtime.h>
#include <hip/hip_bf16.h>
#include <stdint.h>

// DelayedDMD: BS=64, D=256, M=512, m_prox=10 (fixed). A-orientation algebra:
//   G1 = Y1@Y1^T (sym), G21 = Y2@Y1^T
//   q = P^T y1, Piy1 = P y1, k = 1/(1+y1.Piy1)
//   w = y1 - G1 q ; u = G21 q
//   negE = -(P@G1 + k y1 w^T)  [bf16]
//   V'   = G21@P^T + k (y2-u) y1^T  [bf16]
//   x10: A <- A + V' + A@negE^T  == (transposed) B <- B + V'^T + negE@B, B=A^T
//   out1 = A_10 ; out2 = P - k Piy1 q^T   (P taken from bf16 Pb: err ~6e-6)
// R4 == R3 resubmit (R3 bench died on container acquisition, not kernel):
//   - prep2d reads fp32 Y DIRECTLY (no bf16 pre-pass round trip, -64MB):
//     [128x32] fp32 swizzled LDS, 1-barrier dbuf, next-chunk loads under MFMA,
//     in-reg f2b -> bit-exact vs previous rounds.
//   - out2 tail reads Pb (8.4MB) not P (67MB).
//   - iterk-T: iterate B=A^T. Same products/k-order (bit-exact) but C-frag's 4
//     consecutive rows are contiguous in the [j][i] shadow: 8x ds_write_b64
//     (swizzled, <=2-way) instead of 32x ds_write_b16; A/V/out1 all 16B vector.
//   - XCD-aware swizzles kept everywhere (same-batch blocks share one L2).

#define BSZ 64
#define DD 256
#define MM 512

typedef __attribute__((ext_vector_type(8))) short short8;
typedef __attribute__((ext_vector_type(4))) float f32x4;

__device__ __forceinline__ unsigned short f2b(float f) {
    unsigned int u = __float_as_uint(f);
    unsigned int r = (u + 0x7fffu + ((u >> 16) & 1u)) >> 16;
    return (unsigned short)r;
}
__device__ __forceinline__ float b2f(unsigned short s) {
    return __uint_as_float(((unsigned int)s) << 16);
}
__device__ __forceinline__ short8 mk8(const float4 a, const float4 b) {
    short8 r;
    r[0] = (short)f2b(a.x); r[1] = (short)f2b(a.y);
    r[2] = (short)f2b(a.z); r[3] = (short)f2b(a.w);
    r[4] = (short)f2b(b.x); r[5] = (short)f2b(b.y);
    r[6] = (short)f2b(b.z); r[7] = (short)f2b(b.w);
    return r;
}
// HBM -> LDS direct, 16B per lane. LDS dest must be wave-uniform base + lane*16.
__device__ __forceinline__ void gll16(const void* g, void* l) {
    __builtin_amdgcn_global_load_lds(
        (const __attribute__((address_space(1))) unsigned int*)g,
        (__attribute__((address_space(3))) unsigned int*)l, 16, 0, 0);
}

// vec per batch (768 f): [0,256) Piy1 | [256,512) q | [512] k

// ---------------- L1: P-conv + Piy1 + q-partials (512 blocks, 8/batch) ----------------
__global__ __launch_bounds__(256)
void prep1(const float* __restrict__ P, const float* __restrict__ y1g,
           unsigned short* __restrict__ Pb, float* __restrict__ vec,
           float* __restrict__ qpart)
{
    const int blk = blockIdx.x, t = threadIdx.x;
    const int b = blk >> 3, rs = (blk & 7) * 32;
    const long base = (long)b * DD * DD;
    const int wv = t >> 6, ln = t & 63;
    __shared__ float sy1[DD];
    __shared__ float qsh[4][DD];
    sy1[t] = y1g[b * DD + t];
    __syncthreads();
    const int col4 = ln * 4;
    const float4 yv = *(const float4*)(sy1 + col4);
    float4 pr[8];
#pragma unroll
    for (int i = 0; i < 8; ++i) {
        const int row = rs + i * 4 + wv;
        pr[i] = *(const float4*)(P + base + (long)row * DD + col4);
    }
    float ql0 = 0.f, ql1 = 0.f, ql2 = 0.f, ql3 = 0.f;
#pragma unroll
    for (int i = 0; i < 8; ++i) {
        const int row = rs + i * 4 + wv;          // all 64 lanes of wave share this row
        const long o = base + (long)row * DD + col4;
        const float4 p = pr[i];
        ushort4 u;
        u.x = f2b(p.x); u.y = f2b(p.y); u.z = f2b(p.z); u.w = f2b(p.w);
        *(ushort4*)(Pb + o) = u;
        const float yr = sy1[row];
        ql0 += yr * p.x; ql1 += yr * p.y; ql2 += yr * p.z; ql3 += yr * p.w;
        float s = p.x * yv.x + p.y * yv.y + p.z * yv.z + p.w * yv.w;   // Piy1 partial
#pragma unroll
        for (int off = 32; off; off >>= 1) s += __shfl_down(s, off, 64);
        if (ln == 0) vec[(long)b * 768 + row] = s;
    }
    *(float4*)(qsh[wv] + col4) = make_float4(ql0, ql1, ql2, ql3);
    __syncthreads();
    qpart[((long)blk) * DD + t] = qsh[0][t] + qsh[1][t] + qsh[2][t] + qsh[3][t];
}

// ---- L2: fused G1+G21 gemms from fp32 Y (blocks 0..255) + finalize (256..319) ----
__global__ __launch_bounds__(256, 1)
void prep2d(const float* __restrict__ Y1, const float* __restrict__ Y2,
            const float* __restrict__ y1g, const float* __restrict__ qpart,
            unsigned short* __restrict__ G1b, unsigned short* __restrict__ G21b,
            float* __restrict__ vec)
{
    const int blk = blockIdx.x, t = threadIdx.x;
    if (blk >= 256) {
        // finalize: q = sum of 8 partials; k = 1/(1 + y1.Piy1)
        const int b = blk - 256;
        float* vb = vec + (long)b * 768;
        const float* qp = qpart + (long)b * 8 * DD;
        float qv = 0.f;
#pragma unroll
        for (int c = 0; c < 8; ++c) qv += qp[c * DD + t];
        vb[256 + t] = qv;
        __shared__ float red[256];
        red[t] = vb[t] * y1g[b * DD + t];
        __syncthreads();
        for (int s = 128; s; s >>= 1) { if (t < s) red[t] += red[t + s]; __syncthreads(); }
        if (t == 0) vb[512] = 1.0f / (1.0f + red[0]);
        return;
    }
    __shared__ __align__(16) float Sf[2][3][128 * 32];   // 96 KB, swizzled fp32
    // XCD swizzle: 4 quads of a batch on one XCD -> Y panels L2-hit
    const int b = (blk & 7) + 8 * (blk >> 5), quad = (blk >> 3) & 3;
    const int i0 = (quad >> 1) * 128, j0 = (quad & 1) * 128;
    const float* A1 = Y1 + (long)b * DD * MM + (long)i0 * MM;
    const float* A2 = Y2 + (long)b * DD * MM + (long)i0 * MM;
    const float* By = Y1 + (long)b * DD * MM + (long)j0 * MM;
    const int wv = t >> 6, ln = t & 63;
    const int lr = ln & 15, qd = ln >> 4;
    const int mh = (wv >> 1) * 64, nh = (wv & 1) * 64;
    f32x4 acc1[4][4] = {}, acc2[4][4] = {};
    float4 fa[4], fb[4], fc[4];

#define P2LOAD(kc)                                                            \
    _Pragma("unroll")                                                         \
    for (int i = 0; i < 4; ++i) {                                             \
        const int s = i * 256 + t, row = s >> 3, c4 = s & 7;                  \
        const long go = (long)row * MM + (kc) * 32 + c4 * 4;                  \
        fa[i] = *(const float4*)(A1 + go);                                    \
        fb[i] = *(const float4*)(A2 + go);                                    \
        fc[i] = *(const float4*)(By + go);                                    \
    }

    P2LOAD(0);
    for (int kc = 0; kc < 16; ++kc) {
        const int u = kc & 1;
#pragma unroll
        for (int i = 0; i < 4; ++i) {
            const int s = i * 256 + t, row = s >> 3, c4 = s & 7;
            const int o = row * 128 + ((c4 ^ (row & 7)) << 4);
            *(float4*)((char*)Sf[u][0] + o) = fa[i];
            *(float4*)((char*)Sf[u][1] + o) = fb[i];
            *(float4*)((char*)Sf[u][2] + o) = fc[i];
        }
        __syncthreads();      // buf u ready; also fences MFMA(kc-1) reads of buf u^1
        if (kc < 15) { P2LOAD(kc + 1); }   // in flight under MFMA
        short8 a1[4], a2[4], bf[4];
#pragma unroll
        for (int mt = 0; mt < 4; ++mt) {
            const int r = mh + mt * 16 + lr;
            const int g0 = ((2 * qd) ^ (r & 7)) << 4, g1 = ((2 * qd + 1) ^ (r & 7)) << 4;
            const char* p0 = (const char*)Sf[u][0] + r * 128;
            const char* p1 = (const char*)Sf[u][1] + r * 128;
            a1[mt] = mk8(*(const float4*)(p0 + g0), *(const float4*)(p0 + g1));
            a2[mt] = mk8(*(const float4*)(p1 + g0), *(const float4*)(p1 + g1));
        }
#pragma unroll
        for (int nt = 0; nt < 4; ++nt) {
            const int r = nh + nt * 16 + lr;
            const int g0 = ((2 * qd) ^ (r & 7)) << 4, g1 = ((2 * qd + 1) ^ (r & 7)) << 4;
            const char* p2 = (const char*)Sf[u][2] + r * 128;
            bf[nt] = mk8(*(const float4*)(p2 + g0), *(const float4*)(p2 + g1));
        }
#pragma unroll
        for (int mt = 0; mt < 4; ++mt)
#pragma unroll
            for (int nt = 0; nt < 4; ++nt) {
                acc1[mt][nt] = __builtin_amdgcn_mfma_f32_16x16x32_bf16(
                    a1[mt], bf[nt], acc1[mt][nt], 0, 0, 0);
                acc2[mt][nt] = __builtin_amdgcn_mfma_f32_16x16x32_bf16(
                    a2[mt], bf[nt], acc2[mt][nt], 0, 0, 0);
            }
    }
#undef P2LOAD
    unsigned short* O1 = G1b  + (long)b * DD * DD;
    unsigned short* O2 = G21b + (long)b * DD * DD;
#pragma unroll
    for (int mt = 0; mt < 4; ++mt)
#pragma unroll
        for (int nt = 0; nt < 4; ++nt) {
            const int gr0 = i0 + mh + mt * 16 + qd * 4;
            const int gc  = j0 + nh + nt * 16 + lr;
#pragma unroll
            for (int r = 0; r < 4; ++r) {
                O1[(long)(gr0 + r) * DD + gc] = f2b(acc1[mt][nt][r]);
                O2[(long)(gr0 + r) * DD + gc] = f2b(acc2[mt][nt][r]);
            }
        }
}

// ---- L3: negE (sel=0) / V' (sel=1), 512 blocks, BK=64, gload_lds + dbuf ----
__global__ __launch_bounds__(256)
void gemmEV(const unsigned short* __restrict__ Pb, const unsigned short* __restrict__ G1b,
            const unsigned short* __restrict__ G21b,
            const float* __restrict__ y1g, const float* __restrict__ y2g,
            const float* __restrict__ vec,
            unsigned short* __restrict__ Enb, unsigned short* __restrict__ Vpb)
{
    __shared__ __align__(16) unsigned short S[2][2][128 * 64];   // 64 KB
    __shared__ float qs[DD], s1[DD], s2[DD];
    const int blk = blockIdx.x, t = threadIdx.x;
    // XCD swizzle: 8 blocks of a batch share one XCD's L2
    const int b = (blk & 7) + 8 * (blk >> 6);
    const int rem = (blk >> 3) & 7, sel = rem >> 2, quad = rem & 3;
    const int i0 = (quad >> 1) * 128, j0 = (quad & 1) * 128;
    const char* Ab = (const char*)((sel ? G21b : Pb) + (long)b * DD * DD + (long)i0 * DD);
    const char* Bb = (const char*)((sel ? Pb : G1b) + (long)b * DD * DD + (long)j0 * DD);
    unsigned short* Ob = (sel ? Vpb : Enb) + (long)b * DD * DD;
    const float* vb = vec + (long)b * 768;
    const int wv = t >> 6, ln = t & 63;
    const int lr = ln & 15, qd = ln >> 4;
    const int mh = (wv >> 1) * 64, nh = (wv & 1) * 64;
    const int srow = t >> 3;
    const int sc = (t & 7) * 16;

    qs[t] = vb[256 + t];
    s1[t] = y1g[b * DD + t];
    s2[t] = y2g[b * DD + t];

    f32x4 acc[4][4] = {};
    float dot[4] = {0.f, 0.f, 0.f, 0.f};   // sel0: G1q partial per nt; sel1: G21q per mt

#define GEVSTAGE(u, kc)                                                           \
    _Pragma("unroll")                                                             \
    for (int i = 0; i < 4; ++i) {                                                 \
        const int row = i * 32 + srow;                                            \
        const int gco = (kc) * 128 + (sc ^ ((row & 7) << 4));                     \
        const int lo = row * 128 + sc;                                            \
        gll16(Ab + (long)row * 512 + gco, (char*)S[u][0] + lo);                   \
        gll16(Bb + (long)row * 512 + gco, (char*)S[u][1] + lo);                   \
    }

    GEVSTAGE(0, 0);
    for (int kc = 0; kc < 4; ++kc) {
        __syncthreads();
        if (kc < 3) { GEVSTAGE((kc + 1) & 1, kc + 1); }
        const unsigned short (*Su)[128 * 64] = S[kc & 1];
#pragma unroll
        for (int kc2 = 0; kc2 < 2; ++kc2) {
            const int kb = kc2 * 64 + qd * 16;   // byte offset within 128B row
            short8 af[4], bfr[4];
#pragma unroll
            for (int mt = 0; mt < 4; ++mt) {
                const int row = mh + mt * 16 + lr;
                af[mt] = *(const short8*)((const char*)Su[0] + row * 128 +
                                          (kb ^ ((row & 7) << 4)));
            }
#pragma unroll
            for (int nt = 0; nt < 4; ++nt) {
                const int row = nh + nt * 16 + lr;
                bfr[nt] = *(const short8*)((const char*)Su[1] + row * 128 +
                                           (kb ^ ((row & 7) << 4)));
            }
            const int kel = kc * 64 + kc2 * 32 + qd * 8;   // element k of this frag
            const float4 qa = *(const float4*)(qs + kel);
            const float4 qb = *(const float4*)(qs + kel + 4);
            const float qf[8] = {qa.x, qa.y, qa.z, qa.w, qb.x, qb.y, qb.z, qb.w};
            if (!sel) {
#pragma unroll
                for (int nt = 0; nt < 4; ++nt)
#pragma unroll
                    for (int j = 0; j < 8; ++j)
                        dot[nt] += b2f((unsigned short)bfr[nt][j]) * qf[j];
            } else {
#pragma unroll
                for (int mt = 0; mt < 4; ++mt)
#pragma unroll
                    for (int j = 0; j < 8; ++j)
                        dot[mt] += b2f((unsigned short)af[mt][j]) * qf[j];
            }
#pragma unroll
            for (int mt = 0; mt < 4; ++mt)
#pragma unroll
                for (int nt = 0; nt < 4; ++nt)
                    acc[mt][nt] = __builtin_amdgcn_mfma_f32_16x16x32_bf16(
                        af[mt], bfr[nt], acc[mt][nt], 0, 0, 0);
        }
    }
#undef GEVSTAGE
#pragma unroll
    for (int i = 0; i < 4; ++i) {
        dot[i] += __shfl_xor(dot[i], 16, 64);
        dot[i] += __shfl_xor(dot[i], 32, 64);
    }
    const float kk = vb[512];
#pragma unroll
    for (int mt = 0; mt < 4; ++mt) {
#pragma unroll
        for (int nt = 0; nt < 4; ++nt) {
            const int gr0 = i0 + mh + mt * 16 + qd * 4;
            const int gc  = j0 + nh + nt * 16 + lr;
            if (!sel) {
                const float cw = s1[gc] - dot[nt];   // w[col]
#pragma unroll
                for (int r = 0; r < 4; ++r) {
                    const float rv = kk * s1[gr0 + r];
                    Ob[(long)(gr0 + r) * DD + gc] = f2b(-(acc[mt][nt][r] + rv * cw));
                }
            } else {
                const float cv = s1[gc];
#pragma unroll
                for (int r = 0; r < 4; ++r) {
                    const float uv = __shfl(dot[mt], qd * 4 + r, 64);   // u[row]
                    const float rv = kk * (s2[gr0 + r] - uv);
                    Ob[(long)(gr0 + r) * DD + gc] = f2b(acc[mt][nt][r] + rv * cv);
                }
            }
        }
    }
}

// ---- L4: transposed 10-step iterate (0..511) + out2 tail from Pb (512..767) ----
// B = A^T; B += V'^T + negE@B. Thread frag = B[i..i+3][j] = A[j][i..i+3]:
// contiguous in the [j][i] shadow AND in global A/V/out1 -> all 16B vector ops.
__global__ __launch_bounds__(256, 2)
void iterk(const float* __restrict__ A_start, const unsigned short* __restrict__ Enb,
           const unsigned short* __restrict__ Vpb,
           const unsigned short* __restrict__ Pb, const float* __restrict__ vec,
           float* __restrict__ out1, float* __restrict__ out2)
{
    const int blk = blockIdx.x, t = threadIdx.x;
    if (blk >= 512) {
        // out2 = P - k Piy1 q^T  (P from bf16 Pb; err ~6e-6 << absmax 1.15e-3)
        const int c = blk - 512, b = (c & 7) + 8 * (c >> 5), rs = ((c >> 3) & 3) * 64;
        const long base = (long)b * DD * DD;
        const float* vb = vec + (long)b * 768;
        const float kk = vb[512];
#pragma unroll 4
        for (int i = 0; i < 16; ++i) {
            const int idx = rs * DD + (i * 256 + t) * 4;
            const int row = idx >> 8, col = idx & 255;
            const float kPi = kk * vb[row];
            const ushort4 pu = *(const ushort4*)(Pb + base + idx);
            const float4 q = *(const float4*)(vb + 256 + col);
            float4 rr;
            rr.x = b2f(pu.x) - kPi * q.x; rr.y = b2f(pu.y) - kPi * q.y;
            rr.z = b2f(pu.z) - kPi * q.z; rr.w = b2f(pu.w) - kPi * q.w;
            *(float4*)(out2 + base + idx) = rr;
        }
        return;
    }
    __shared__ __align__(16) unsigned short Xsh[32 * 256];   // [j][i] 16KB, swizzled
    // XCD swizzle: 8 strip-blocks of a batch share one XCD -> E panel L2-hit
    const int b = (blk & 7) + 8 * (blk >> 6), r0 = ((blk >> 3) & 7) * 32;
    const long base = (long)b * DD * DD;
    const float* Ab = A_start + base;
    const unsigned short* Eb = Enb + base;
    const unsigned short* Vb = Vpb + base;
    float* Ob = out1 + base;
    const int wv = t >> 6, ln = t & 63;
    const int lr = ln & 15, qd = ln >> 4;
    const int ib = wv * 64;                 // wave's i-range [ib, ib+64)

    f32x4 acc[4][2], vv[4][2];
    short8 ef[4][8];

#pragma unroll
    for (int it = 0; it < 4; ++it)
#pragma unroll
        for (int jt = 0; jt < 2; ++jt) {
            const long o = (long)(r0 + jt * 16 + lr) * DD + ib + it * 16 + qd * 4;
            acc[it][jt] = *(const f32x4*)(Ab + o);
            const ushort4 vu = *(const ushort4*)(Vb + o);
            vv[it][jt][0] = b2f(vu.x); vv[it][jt][1] = b2f(vu.y);
            vv[it][jt][2] = b2f(vu.z); vv[it][jt][3] = b2f(vu.w);
        }
#pragma unroll
    for (int it = 0; it < 4; ++it) {
        const long ro = (long)(ib + it * 16 + lr) * DD;
#pragma unroll
        for (int kc = 0; kc < 8; ++kc)
            ef[it][kc] = *(const short8*)(Eb + ro + kc * 32 + qd * 8);
    }

    const int gpart = wv * 8 + (qd >> 1), off8 = (qd & 1) * 8;

#pragma unroll 1
    for (int s = 0; s < 10; ++s) {
        // shadow write: X[j][i..i+3] as one b64 (swizzled granules, <=2-way)
#pragma unroll
        for (int it = 0; it < 4; ++it)
#pragma unroll
            for (int jt = 0; jt < 2; ++jt) {
                const int j = jt * 16 + lr;
                const int g = (gpart + it * 2) ^ ((j & 7) << 1);
                const unsigned int p0 = (unsigned int)f2b(acc[it][jt][0]) |
                                        ((unsigned int)f2b(acc[it][jt][1]) << 16);
                const unsigned int p1 = (unsigned int)f2b(acc[it][jt][2]) |
                                        ((unsigned int)f2b(acc[it][jt][3]) << 16);
                *(uint2*)((char*)Xsh + j * 512 + g * 16 + off8) = make_uint2(p0, p1);
                acc[it][jt] += vv[it][jt];
            }
        __syncthreads();
#pragma unroll
        for (int kc = 0; kc < 8; ++kc) {
            short8 bf[2];
#pragma unroll
            for (int jt = 0; jt < 2; ++jt) {
                const int j = jt * 16 + lr;
                const int g = (kc * 4 + qd) ^ ((j & 7) << 1);
                bf[jt] = *(const short8*)((char*)Xsh + j * 512 + g * 16);
            }
#pragma unroll
            for (int it = 0; it < 4; ++it)
#pragma unroll
                for (int jt = 0; jt < 2; ++jt)
                    acc[it][jt] = __builtin_amdgcn_mfma_f32_16x16x32_bf16(
                        ef[it][kc], bf[jt], acc[it][jt], 0, 0, 0);
        }
        __syncthreads();
    }

#pragma unroll
    for (int it = 0; it < 4; ++it)
#pragma unroll
        for (int jt = 0; jt < 2; ++jt) {
            const long o = (long)(r0 + jt * 16 + lr) * DD + ib + it * 16 + qd * 4;
            *(f32x4*)(Ob + o) = acc[it][jt];
        }
}

extern "C" void kernel_launch(void* const* d_in, const int* in_sizes, int n_in,
                              void* d_out, int out_size, void* d_ws, size_t ws_size,
                              hipStream_t stream)
{
    const float* A_start = (const float*)d_in[0];
    const float* Y1      = (const float*)d_in[1];
    const float* Y2      = (const float*)d_in[2];
    const float* y1      = (const float*)d_in[3];
    const float* y2      = (const float*)d_in[4];
    const float* P       = (const float*)d_in[5];

    const long EL2 = (long)BSZ * DD * DD;   // 4,194,304

    float* out1 = (float*)d_out;
    float* out2 = out1 + EL2;

    char* w8 = (char*)d_ws;                          // ~42.7 MB used
    unsigned short* Pb    = (unsigned short*)(w8);                 // 8MB
    unsigned short* G1b   = (unsigned short*)(w8 + 8388608);       // 8MB
    unsigned short* G21b  = (unsigned short*)(w8 + 16777216);      // 8MB
    unsigned short* Enb   = (unsigned short*)(w8 + 25165824);      // 8MB
    unsigned short* Vpb   = (unsigned short*)(w8 + 33554432);      // 8MB
    float*          vec   = (float*)(w8 + 41943040);               // 64*768*4
    float*          qpart = (float*)(w8 + 42139648);               // 64*8*256*4

    const dim3 blk(256);

    prep1<<<512, blk, 0, stream>>>(P, y1, Pb, vec, qpart);
    prep2d<<<320, blk, 0, stream>>>(Y1, Y2, y1, qpart, G1b, G21b, vec);
    gemmEV<<<512, blk, 0, stream>>>(Pb, G1b, G21b, y1, y2, vec, Enb, Vpb);
    iterk<<<768, blk, 0, stream>>>(A_start, Enb, Vpb, Pb, vec, out1, out2);
}

// Round 5
// 194.304 us; speedup vs baseline: 1.4479x; 1.4479x over previous
//
#include <hip/hip_runtime.h>
#include <hip/hip_bf16.h>
#include <stdint.h>

// DelayedDMD: BS=64, D=256, M=512, m_prox=10 (fixed). A-orientation algebra:
//   G1 = Y1@Y1^T (sym), G21 = Y2@Y1^T
//   q = P^T y1, Piy1 = P y1, k = 1/(1+y1.Piy1)
//   w = y1 - G1 q ; u = G21 q
//   negE = -(P@G1 + k y1 w^T)  [bf16]
//   V'   = G21@P^T + k (y2-u) y1^T  [bf16]
//   x10: A <- A + V' + A@negE^T  == (transposed) B <- B + V'^T + negE@B, B=A^T
//   out1 = A_10 ; out2 = P - k Piy1 q^T   (P taken from bf16 Pb: err ~6e-6)
// R5: R4's prep2d (fp32 LDS, READ-side conversion, 1 wave/SIMD) was a 117us
// latency chain (8.5M bank conflicts, all pipes <8%). prep2e fixes:
//   - WRITE-side f2b (once per element), bf16 LDS, single ds_read_b128 + MFMA.
//   - 64x128 tiles -> 512 blocks (2/CU), 32KB LDS dbuf, ~155 VGPR.
//   - row-pair 128B-line layout, slot XOR line&7 -> 2-way max on reads (free).
//   - prefetch regs live only between barriers (no spill).
// prep1 / gemmEV / iterk-T / out2-from-Pb unchanged from R4 (none in top-5).

#define BSZ 64
#define DD 256
#define MM 512

typedef __attribute__((ext_vector_type(8))) short short8;
typedef __attribute__((ext_vector_type(4))) float f32x4;

__device__ __forceinline__ unsigned short f2b(float f) {
    unsigned int u = __float_as_uint(f);
    unsigned int r = (u + 0x7fffu + ((u >> 16) & 1u)) >> 16;
    return (unsigned short)r;
}
__device__ __forceinline__ float b2f(unsigned short s) {
    return __uint_as_float(((unsigned int)s) << 16);
}
// HBM -> LDS direct, 16B per lane. LDS dest must be wave-uniform base + lane*16.
__device__ __forceinline__ void gll16(const void* g, void* l) {
    __builtin_amdgcn_global_load_lds(
        (const __attribute__((address_space(1))) unsigned int*)g,
        (__attribute__((address_space(3))) unsigned int*)l, 16, 0, 0);
}

// vec per batch (768 f): [0,256) Piy1 | [256,512) q | [512] k

// ---------------- L1: P-conv + Piy1 + q-partials (512 blocks, 8/batch) ----------------
__global__ __launch_bounds__(256)
void prep1(const float* __restrict__ P, const float* __restrict__ y1g,
           unsigned short* __restrict__ Pb, float* __restrict__ vec,
           float* __restrict__ qpart)
{
    const int blk = blockIdx.x, t = threadIdx.x;
    const int b = blk >> 3, rs = (blk & 7) * 32;
    const long base = (long)b * DD * DD;
    const int wv = t >> 6, ln = t & 63;
    __shared__ float sy1[DD];
    __shared__ float qsh[4][DD];
    sy1[t] = y1g[b * DD + t];
    __syncthreads();
    const int col4 = ln * 4;
    const float4 yv = *(const float4*)(sy1 + col4);
    float4 pr[8];
#pragma unroll
    for (int i = 0; i < 8; ++i) {
        const int row = rs + i * 4 + wv;
        pr[i] = *(const float4*)(P + base + (long)row * DD + col4);
    }
    float ql0 = 0.f, ql1 = 0.f, ql2 = 0.f, ql3 = 0.f;
#pragma unroll
    for (int i = 0; i < 8; ++i) {
        const int row = rs + i * 4 + wv;          // all 64 lanes of wave share this row
        const long o = base + (long)row * DD + col4;
        const float4 p = pr[i];
        ushort4 u;
        u.x = f2b(p.x); u.y = f2b(p.y); u.z = f2b(p.z); u.w = f2b(p.w);
        *(ushort4*)(Pb + o) = u;
        const float yr = sy1[row];
        ql0 += yr * p.x; ql1 += yr * p.y; ql2 += yr * p.z; ql3 += yr * p.w;
        float s = p.x * yv.x + p.y * yv.y + p.z * yv.z + p.w * yv.w;   // Piy1 partial
#pragma unroll
        for (int off = 32; off; off >>= 1) s += __shfl_down(s, off, 64);
        if (ln == 0) vec[(long)b * 768 + row] = s;
    }
    *(float4*)(qsh[wv] + col4) = make_float4(ql0, ql1, ql2, ql3);
    __syncthreads();
    qpart[((long)blk) * DD + t] = qsh[0][t] + qsh[1][t] + qsh[2][t] + qsh[3][t];
}

// ---- L2: fused G1+G21 gemms, 64x128 tiles (blocks 0..511) + finalize (512..575) ----
// fp32 Y loads -> in-reg f2b -> bf16 LDS (write-side conversion). BK=32, dbuf.
// LDS layout: row-pairs share a 128B line; 16B slot g8=((row&1)<<2)+(k>>3),
// swizzled g8^(line&7); 8B half-slot (k>>2)&1. Reads: 2-way max (free).
__global__ __launch_bounds__(256)
void prep2e(const float* __restrict__ Y1, const float* __restrict__ Y2,
            const float* __restrict__ y1g, const float* __restrict__ qpart,
            unsigned short* __restrict__ G1b, unsigned short* __restrict__ G21b,
            float* __restrict__ vec)
{
    const int blk = blockIdx.x, t = threadIdx.x;
    if (blk >= 512) {
        // finalize: q = sum of 8 partials; k = 1/(1 + y1.Piy1)
        const int b = blk - 512;
        float* vb = vec + (long)b * 768;
        const float* qp = qpart + (long)b * 8 * DD;
        float qv = 0.f;
#pragma unroll
        for (int c = 0; c < 8; ++c) qv += qp[c * DD + t];
        vb[256 + t] = qv;
        __shared__ float red[256];
        red[t] = vb[t] * y1g[b * DD + t];
        __syncthreads();
        for (int s = 128; s; s >>= 1) { if (t < s) red[t] += red[t + s]; __syncthreads(); }
        if (t == 0) vb[512] = 1.0f / (1.0f + red[0]);
        return;
    }
    __shared__ __align__(16) unsigned short S[2][8192];   // 32 KB: A1@0 A2@4K By@8K (bytes)
    // XCD swizzle: blk = tile*64 + (b>>3)*8 + (b&7); all 8 tiles of b on one XCD
    const int b = (blk & 7) + 8 * ((blk >> 3) & 7), tile = blk >> 6;
    const int i0 = (tile & 3) * 64, j0 = (tile >> 2) * 128;
    const float* A1 = Y1 + (long)b * DD * MM + (long)i0 * MM;
    const float* A2 = Y2 + (long)b * DD * MM + (long)i0 * MM;
    const float* By = Y1 + (long)b * DD * MM + (long)j0 * MM;
    const int wv = t >> 6, ln = t & 63;
    const int lr = ln & 15, qd = ln >> 4;
    const int wr = wv >> 1, wc = wv & 1;       // wave tile: rows wr*32+[0,32), cols wc*64+[0,64)
    f32x4 acc1[2][4] = {}, acc2[2][4] = {};
    float4 fr[8];

#define P2LOAD(kc)                                                            \
    do {                                                                      \
        _Pragma("unroll")                                                     \
        for (int i = 0; i < 2; ++i) {                                         \
            const int s = i * 256 + t, row = s >> 3, c4 = s & 7;              \
            const long go = (long)row * MM + (kc) * 32 + c4 * 4;              \
            fr[i]     = *(const float4*)(A1 + go);                            \
            fr[2 + i] = *(const float4*)(A2 + go);                            \
        }                                                                     \
        _Pragma("unroll")                                                     \
        for (int i = 0; i < 4; ++i) {                                         \
            const int s = i * 256 + t, row = s >> 3, c4 = s & 7;              \
            const long go = (long)row * MM + (kc) * 32 + c4 * 4;              \
            fr[4 + i] = *(const float4*)(By + go);                            \
        }                                                                     \
    } while (0)

    P2LOAD(0);
    for (int kc = 0; kc < 16; ++kc) {
        const int u = kc & 1;
        // ---- convert + swizzled bf16 stores (consumes fr) ----
#pragma unroll
        for (int i = 0; i < 2; ++i) {
            const int s = i * 256 + t, row = s >> 3, c4 = s & 7;
            const int line = row >> 1;
            const int g8 = (((row & 1) << 2) + (c4 >> 1)) ^ (line & 7);
            const int off = line * 128 + (g8 << 4) + ((c4 & 1) << 3);
            ushort4 ua, ub;
            ua.x = f2b(fr[i].x); ua.y = f2b(fr[i].y);
            ua.z = f2b(fr[i].z); ua.w = f2b(fr[i].w);
            ub.x = f2b(fr[2 + i].x); ub.y = f2b(fr[2 + i].y);
            ub.z = f2b(fr[2 + i].z); ub.w = f2b(fr[2 + i].w);
            *(ushort4*)((char*)S[u] + off) = ua;
            *(ushort4*)((char*)S[u] + 4096 + off) = ub;
        }
#pragma unroll
        for (int i = 0; i < 4; ++i) {
            const int s = i * 256 + t, row = s >> 3, c4 = s & 7;
            const int line = row >> 1;
            const int g8 = (((row & 1) << 2) + (c4 >> 1)) ^ (line & 7);
            const int off = line * 128 + (g8 << 4) + ((c4 & 1) << 3);
            ushort4 uc;
            uc.x = f2b(fr[4 + i].x); uc.y = f2b(fr[4 + i].y);
            uc.z = f2b(fr[4 + i].z); uc.w = f2b(fr[4 + i].w);
            *(ushort4*)((char*)S[u] + 8192 + off) = uc;
        }
        __syncthreads();
        if (kc < 15) { P2LOAD(kc + 1); }        // in flight under ds_read+MFMA
        // ---- fragments (single b128 each) + MFMA ----
        short8 a1[2], a2[2], bfr[4];
#pragma unroll
        for (int mt = 0; mt < 2; ++mt) {
            const int row = wr * 32 + mt * 16 + lr;
            const int line = row >> 1;
            const int off = line * 128 + (((((row & 1) << 2) + qd) ^ (line & 7)) << 4);
            a1[mt] = *(const short8*)((const char*)S[u] + off);
            a2[mt] = *(const short8*)((const char*)S[u] + 4096 + off);
        }
#pragma unroll
        for (int nt = 0; nt < 4; ++nt) {
            const int row = wc * 64 + nt * 16 + lr;
            const int line = row >> 1;
            const int off = line * 128 + (((((row & 1) << 2) + qd) ^ (line & 7)) << 4);
            bfr[nt] = *(const short8*)((const char*)S[u] + 8192 + off);
        }
#pragma unroll
        for (int mt = 0; mt < 2; ++mt)
#pragma unroll
            for (int nt = 0; nt < 4; ++nt) {
                acc1[mt][nt] = __builtin_amdgcn_mfma_f32_16x16x32_bf16(
                    a1[mt], bfr[nt], acc1[mt][nt], 0, 0, 0);
                acc2[mt][nt] = __builtin_amdgcn_mfma_f32_16x16x32_bf16(
                    a2[mt], bfr[nt], acc2[mt][nt], 0, 0, 0);
            }
    }
#undef P2LOAD
    unsigned short* O1 = G1b  + (long)b * DD * DD;
    unsigned short* O2 = G21b + (long)b * DD * DD;
#pragma unroll
    for (int mt = 0; mt < 2; ++mt)
#pragma unroll
        for (int nt = 0; nt < 4; ++nt) {
            const int gr0 = i0 + wr * 32 + mt * 16 + qd * 4;
            const int gc  = j0 + wc * 64 + nt * 16 + lr;
#pragma unroll
            for (int r = 0; r < 4; ++r) {
                O1[(long)(gr0 + r) * DD + gc] = f2b(acc1[mt][nt][r]);
                O2[(long)(gr0 + r) * DD + gc] = f2b(acc2[mt][nt][r]);
            }
        }
}

// ---- L3: negE (sel=0) / V' (sel=1), 512 blocks, BK=64, gload_lds + dbuf ----
__global__ __launch_bounds__(256)
void gemmEV(const unsigned short* __restrict__ Pb, const unsigned short* __restrict__ G1b,
            const unsigned short* __restrict__ G21b,
            const float* __restrict__ y1g, const float* __restrict__ y2g,
            const float* __restrict__ vec,
            unsigned short* __restrict__ Enb, unsigned short* __restrict__ Vpb)
{
    __shared__ __align__(16) unsigned short S[2][2][128 * 64];   // 64 KB
    __shared__ float qs[DD], s1[DD], s2[DD];
    const int blk = blockIdx.x, t = threadIdx.x;
    // XCD swizzle: 8 blocks of a batch share one XCD's L2
    const int b = (blk & 7) + 8 * (blk >> 6);
    const int rem = (blk >> 3) & 7, sel = rem >> 2, quad = rem & 3;
    const int i0 = (quad >> 1) * 128, j0 = (quad & 1) * 128;
    const char* Ab = (const char*)((sel ? G21b : Pb) + (long)b * DD * DD + (long)i0 * DD);
    const char* Bb = (const char*)((sel ? Pb : G1b) + (long)b * DD * DD + (long)j0 * DD);
    unsigned short* Ob = (sel ? Vpb : Enb) + (long)b * DD * DD;
    const float* vb = vec + (long)b * 768;
    const int wv = t >> 6, ln = t & 63;
    const int lr = ln & 15, qd = ln >> 4;
    const int mh = (wv >> 1) * 64, nh = (wv & 1) * 64;
    const int srow = t >> 3;
    const int sc = (t & 7) * 16;

    qs[t] = vb[256 + t];
    s1[t] = y1g[b * DD + t];
    s2[t] = y2g[b * DD + t];

    f32x4 acc[4][4] = {};
    float dot[4] = {0.f, 0.f, 0.f, 0.f};   // sel0: G1q partial per nt; sel1: G21q per mt

#define GEVSTAGE(u, kc)                                                           \
    _Pragma("unroll")                                                             \
    for (int i = 0; i < 4; ++i) {                                                 \
        const int row = i * 32 + srow;                                            \
        const int gco = (kc) * 128 + (sc ^ ((row & 7) << 4));                     \
        const int lo = row * 128 + sc;                                            \
        gll16(Ab + (long)row * 512 + gco, (char*)S[u][0] + lo);                   \
        gll16(Bb + (long)row * 512 + gco, (char*)S[u][1] + lo);                   \
    }

    GEVSTAGE(0, 0);
    for (int kc = 0; kc < 4; ++kc) {
        __syncthreads();
        if (kc < 3) { GEVSTAGE((kc + 1) & 1, kc + 1); }
        const unsigned short (*Su)[128 * 64] = S[kc & 1];
#pragma unroll
        for (int kc2 = 0; kc2 < 2; ++kc2) {
            const int kb = kc2 * 64 + qd * 16;   // byte offset within 128B row
            short8 af[4], bfr[4];
#pragma unroll
            for (int mt = 0; mt < 4; ++mt) {
                const int row = mh + mt * 16 + lr;
                af[mt] = *(const short8*)((const char*)Su[0] + row * 128 +
                                          (kb ^ ((row & 7) << 4)));
            }
#pragma unroll
            for (int nt = 0; nt < 4; ++nt) {
                const int row = nh + nt * 16 + lr;
                bfr[nt] = *(const short8*)((const char*)Su[1] + row * 128 +
                                           (kb ^ ((row & 7) << 4)));
            }
            const int kel = kc * 64 + kc2 * 32 + qd * 8;   // element k of this frag
            const float4 qa = *(const float4*)(qs + kel);
            const float4 qb = *(const float4*)(qs + kel + 4);
            const float qf[8] = {qa.x, qa.y, qa.z, qa.w, qb.x, qb.y, qb.z, qb.w};
            if (!sel) {
#pragma unroll
                for (int nt = 0; nt < 4; ++nt)
#pragma unroll
                    for (int j = 0; j < 8; ++j)
                        dot[nt] += b2f((unsigned short)bfr[nt][j]) * qf[j];
            } else {
#pragma unroll
                for (int mt = 0; mt < 4; ++mt)
#pragma unroll
                    for (int j = 0; j < 8; ++j)
                        dot[mt] += b2f((unsigned short)af[mt][j]) * qf[j];
            }
#pragma unroll
            for (int mt = 0; mt < 4; ++mt)
#pragma unroll
                for (int nt = 0; nt < 4; ++nt)
                    acc[mt][nt] = __builtin_amdgcn_mfma_f32_16x16x32_bf16(
                        af[mt], bfr[nt], acc[mt][nt], 0, 0, 0);
        }
    }
#undef GEVSTAGE
#pragma unroll
    for (int i = 0; i < 4; ++i) {
        dot[i] += __shfl_xor(dot[i], 16, 64);
        dot[i] += __shfl_xor(dot[i], 32, 64);
    }
    const float kk = vb[512];
#pragma unroll
    for (int mt = 0; mt < 4; ++mt) {
#pragma unroll
        for (int nt = 0; nt < 4; ++nt) {
            const int gr0 = i0 + mh + mt * 16 + qd * 4;
            const int gc  = j0 + nh + nt * 16 + lr;
            if (!sel) {
                const float cw = s1[gc] - dot[nt];   // w[col]
#pragma unroll
                for (int r = 0; r < 4; ++r) {
                    const float rv = kk * s1[gr0 + r];
                    Ob[(long)(gr0 + r) * DD + gc] = f2b(-(acc[mt][nt][r] + rv * cw));
                }
            } else {
                const float cv = s1[gc];
#pragma unroll
                for (int r = 0; r < 4; ++r) {
                    const float uv = __shfl(dot[mt], qd * 4 + r, 64);   // u[row]
                    const float rv = kk * (s2[gr0 + r] - uv);
                    Ob[(long)(gr0 + r) * DD + gc] = f2b(acc[mt][nt][r] + rv * cv);
                }
            }
        }
    }
}

// ---- L4: transposed 10-step iterate (0..511) + out2 tail from Pb (512..767) ----
// B = A^T; B += V'^T + negE@B. Thread frag = B[i..i+3][j] = A[j][i..i+3]:
// contiguous in the [j][i] shadow AND in global A/V/out1 -> all 16B vector ops.
__global__ __launch_bounds__(256, 2)
void iterk(const float* __restrict__ A_start, const unsigned short* __restrict__ Enb,
           const unsigned short* __restrict__ Vpb,
           const unsigned short* __restrict__ Pb, const float* __restrict__ vec,
           float* __restrict__ out1, float* __restrict__ out2)
{
    const int blk = blockIdx.x, t = threadIdx.x;
    if (blk >= 512) {
        // out2 = P - k Piy1 q^T  (P from bf16 Pb; err ~6e-6 << absmax 1.15e-3)
        const int c = blk - 512, b = (c & 7) + 8 * (c >> 5), rs = ((c >> 3) & 3) * 64;
        const long base = (long)b * DD * DD;
        const float* vb = vec + (long)b * 768;
        const float kk = vb[512];
#pragma unroll 4
        for (int i = 0; i < 16; ++i) {
            const int idx = rs * DD + (i * 256 + t) * 4;
            const int row = idx >> 8, col = idx & 255;
            const float kPi = kk * vb[row];
            const ushort4 pu = *(const ushort4*)(Pb + base + idx);
            const float4 q = *(const float4*)(vb + 256 + col);
            float4 rr;
            rr.x = b2f(pu.x) - kPi * q.x; rr.y = b2f(pu.y) - kPi * q.y;
            rr.z = b2f(pu.z) - kPi * q.z; rr.w = b2f(pu.w) - kPi * q.w;
            *(float4*)(out2 + base + idx) = rr;
        }
        return;
    }
    __shared__ __align__(16) unsigned short Xsh[32 * 256];   // [j][i] 16KB, swizzled
    // XCD swizzle: 8 strip-blocks of a batch share one XCD -> E panel L2-hit
    const int b = (blk & 7) + 8 * (blk >> 6), r0 = ((blk >> 3) & 7) * 32;
    const long base = (long)b * DD * DD;
    const float* Ab = A_start + base;
    const unsigned short* Eb = Enb + base;
    const unsigned short* Vb = Vpb + base;
    float* Ob = out1 + base;
    const int wv = t >> 6, ln = t & 63;
    const int lr = ln & 15, qd = ln >> 4;
    const int ib = wv * 64;                 // wave's i-range [ib, ib+64)

    f32x4 acc[4][2], vv[4][2];
    short8 ef[4][8];

#pragma unroll
    for (int it = 0; it < 4; ++it)
#pragma unroll
        for (int jt = 0; jt < 2; ++jt) {
            const long o = (long)(r0 + jt * 16 + lr) * DD + ib + it * 16 + qd * 4;
            acc[it][jt] = *(const f32x4*)(Ab + o);
            const ushort4 vu = *(const ushort4*)(Vb + o);
            vv[it][jt][0] = b2f(vu.x); vv[it][jt][1] = b2f(vu.y);
            vv[it][jt][2] = b2f(vu.z); vv[it][jt][3] = b2f(vu.w);
        }
#pragma unroll
    for (int it = 0; it < 4; ++it) {
        const long ro = (long)(ib + it * 16 + lr) * DD;
#pragma unroll
        for (int kc = 0; kc < 8; ++kc)
            ef[it][kc] = *(const short8*)(Eb + ro + kc * 32 + qd * 8);
    }

    const int gpart = wv * 8 + (qd >> 1), off8 = (qd & 1) * 8;

#pragma unroll 1
    for (int s = 0; s < 10; ++s) {
        // shadow write: X[j][i..i+3] as one b64 (swizzled granules, <=2-way)
#pragma unroll
        for (int it = 0; it < 4; ++it)
#pragma unroll
            for (int jt = 0; jt < 2; ++jt) {
                const int j = jt * 16 + lr;
                const int g = (gpart + it * 2) ^ ((j & 7) << 1);
                const unsigned int p0 = (unsigned int)f2b(acc[it][jt][0]) |
                                        ((unsigned int)f2b(acc[it][jt][1]) << 16);
                const unsigned int p1 = (unsigned int)f2b(acc[it][jt][2]) |
                                        ((unsigned int)f2b(acc[it][jt][3]) << 16);
                *(uint2*)((char*)Xsh + j * 512 + g * 16 + off8) = make_uint2(p0, p1);
                acc[it][jt] += vv[it][jt];
            }
        __syncthreads();
#pragma unroll
        for (int kc = 0; kc < 8; ++kc) {
            short8 bf[2];
#pragma unroll
            for (int jt = 0; jt < 2; ++jt) {
                const int j = jt * 16 + lr;
                const int g = (kc * 4 + qd) ^ ((j & 7) << 1);
                bf[jt] = *(const short8*)((char*)Xsh + j * 512 + g * 16);
            }
#pragma unroll
            for (int it = 0; it < 4; ++it)
#pragma unroll
                for (int jt = 0; jt < 2; ++jt)
                    acc[it][jt] = __builtin_amdgcn_mfma_f32_16x16x32_bf16(
                        ef[it][kc], bf[jt], acc[it][jt], 0, 0, 0);
        }
        __syncthreads();
    }

#pragma unroll
    for (int it = 0; it < 4; ++it)
#pragma unroll
        for (int jt = 0; jt < 2; ++jt) {
            const long o = (long)(r0 + jt * 16 + lr) * DD + ib + it * 16 + qd * 4;
            *(f32x4*)(Ob + o) = acc[it][jt];
        }
}

extern "C" void kernel_launch(void* const* d_in, const int* in_sizes, int n_in,
                              void* d_out, int out_size, void* d_ws, size_t ws_size,
                              hipStream_t stream)
{
    const float* A_start = (const float*)d_in[0];
    const float* Y1      = (const float*)d_in[1];
    const float* Y2      = (const float*)d_in[2];
    const float* y1      = (const float*)d_in[3];
    const float* y2      = (const float*)d_in[4];
    const float* P       = (const float*)d_in[5];

    const long EL2 = (long)BSZ * DD * DD;   // 4,194,304

    float* out1 = (float*)d_out;
    float* out2 = out1 + EL2;

    char* w8 = (char*)d_ws;                          // ~42.7 MB used
    unsigned short* Pb    = (unsigned short*)(w8);                 // 8MB
    unsigned short* G1b   = (unsigned short*)(w8 + 8388608);       // 8MB
    unsigned short* G21b  = (unsigned short*)(w8 + 16777216);      // 8MB
    unsigned short* Enb   = (unsigned short*)(w8 + 25165824);      // 8MB
    unsigned short* Vpb   = (unsigned short*)(w8 + 33554432);      // 8MB
    float*          vec   = (float*)(w8 + 41943040);               // 64*768*4
    float*          qpart = (float*)(w8 + 42139648);               // 64*8*256*4

    const dim3 blk(256);

    prep1<<<512, blk, 0, stream>>>(P, y1, Pb, vec, qpart);
    prep2e<<<576, blk, 0, stream>>>(Y1, Y2, y1, qpart, G1b, G21b, vec);
    gemmEV<<<512, blk, 0, stream>>>(Pb, G1b, G21b, y1, y2, vec, Enb, Vpb);
    iterk<<<768, blk, 0, stream>>>(A_start, Enb, Vpb, Pb, vec, out1, out2);
}